// Round 21
// baseline (106.113 us; speedup 1.0000x reference)
//
#include <hip/hip_runtime.h>

// Problem constants: B=32, L=2, F=65536, D=768
#define BB 32
#define LL 2
#define FF 65536
#define DD 768
#define F4 (FF / 4)        // 16384 float4 per f row
#define LD (LL * DD)       // 1536
#define BL (BB * LD)       // 49152 outputs

#define NSTEPS (FF / 16)   // 4096 K16-steps
#define APREP_BYTES ((size_t)NSTEPS * 64 * 16)      // 4 MB
#define CHUNK_BYTES ((size_t)BL * sizeof(float))    // 196608 B
#define NF 256             // F-chunks; grid (NF, 2) = 512 blocks = 2/CU
#define KS (NSTEPS / NF)   // 16 K16-steps per chunk

typedef __attribute__((ext_vector_type(8)))  short short8;   // 8 bf16 (4 VGPR)
typedef __attribute__((ext_vector_type(16))) float float16;  // 16 fp32 acc

// fp32 -> bf16 round-to-nearest-even (finite inputs)
static __device__ __forceinline__ unsigned bf16rne(float x)
{
    unsigned u = __float_as_uint(x);
    return (u + 0x7fffu + ((u >> 16) & 1u)) >> 16;
}
static __device__ __forceinline__ unsigned packbf(float a, float b)
{
    return bf16rne(a) | (bf16rne(b) << 16);
}

// Prep: build A-fragments. aprep[s][lane] (uint4) = 8 bf16 of
// A[row = lane&31][k = s*16 + (lane>>5)*8 + j], j=0..7, A[b][k] = f[b][k].
__global__ __launch_bounds__(256) void cc_prep_a(
    const float4* __restrict__ f4,     // [32][16384]
    uint4* __restrict__ aprep)         // [4096][64]
{
    int t = blockIdx.x * 256 + threadIdx.x;      // 0 .. 4096*64-1
    if (t >= NSTEPS * 64) return;
    int s = t >> 6;
    int l = t & 63;
    int b = l & 31;
    int k0 = s * 16 + ((l >> 5) << 3);           // multiple of 8
    float4 fa = f4[(size_t)b * F4 + (k0 >> 2)];
    float4 fb = f4[(size_t)b * F4 + (k0 >> 2) + 1];
    uint4 u;
    u.x = packbf(fa.x, fa.y);
    u.y = packbf(fa.z, fa.w);
    u.z = packbf(fb.x, fb.y);
    u.w = packbf(fb.z, fb.w);
    aprep[t] = u;
}

// Stage 1: MFMA partial GEMM with linear weight streaming + 2 blocks/CU.
// grid = (NF, 2); block = 512 (8 waves). Block tile: M=32 x N=768 (full row),
// K-chunk = KS*16 = 256 rows (786 KB). Per K16-step:
//   - stage 16 full rows (48 KB contiguous) into LDS via 48 global_load_lds
//     dwordx4 (1 KB/instr, no VGPR round-trip)
//   - each wave: 3 n-tiles (d = 96*wv + 32*i + col); B-frag = 8 ds_read_b32
//     column gathers (banks = d mod 32, conflict-free) + bf16 cvt +
//     mfma_f32_32x32x16_bf16 (verified layouts).
// Serial stage->compute inside a block, but __launch_bounds__(512,4) yields
// 2 blocks/CU (4 waves/EU, VGPR cap 128 >= ~85 demand; LDS 96 <= 160 KB):
// one block's staging overlaps the other's compute -> HBM never idles.
// (R20 ran 1 block/CU: HBM idle during every compute phase, ~75% duty.)
// C/D layout: col = lane&31, row = (r&3) + 8*(r>>2) + 4*(lane>>5).
__global__ __launch_bounds__(512, 4) void cc_mfma(
    const uint4* __restrict__ aprep,   // [4096][64]
    const float* __restrict__ weight,  // [2][65536][768]
    float* __restrict__ partials)      // [NF][32][1536]
{
    __shared__ float lbuf[16 * DD];    // 48 KB: 16 staged rows

    const int tid  = threadIdx.x;
    const int lane = tid & 63;
    const int wv   = tid >> 6;         // 0..7
    const int c    = blockIdx.x;       // 0..NF-1
    const int l    = blockIdx.y;       // 0..1
    const int col  = lane & 31;
    const int half = lane >> 5;

    // chunk base: rows [c*KS*16, (c+1)*KS*16) of W[l]
    const float4* __restrict__ wchunk =
        (const float4*)(weight + ((size_t)l * FF + (size_t)c * (KS * 16)) * DD);
    float4* lb4 = (float4*)lbuf;

    const uint4* __restrict__ ap = aprep + (size_t)c * KS * 64 + lane;

    float16 acc[3];
#pragma unroll
    for (int i = 0; i < 3; ++i)
#pragma unroll
        for (int r = 0; r < 16; ++r) acc[i][r] = 0.f;

    for (int s = 0; s < KS; ++s) {
        __syncthreads();               // all ds_reads of prev step done
        const float4* __restrict__ gsrc = wchunk + (size_t)s * 3072;
#pragma unroll
        for (int t = 0; t < 6; ++t) {
            int idx = t * 512 + tid;   // wave-uniform LDS base + lane*16
            __builtin_amdgcn_global_load_lds(
                (const __attribute__((address_space(1))) void*)(gsrc + idx),
                (__attribute__((address_space(3))) void*)(lb4 + idx),
                16, 0, 0);
        }
        uint4 av = ap[(size_t)s * 64]; // A-frag (L2/L3), drains with the glls
        __syncthreads();               // vmcnt(0) drain before barrier

        short8 a8 = __builtin_bit_cast(short8, av);
        const int rbase = half * 8;
#pragma unroll
        for (int i = 0; i < 3; ++i) {
            const int d = 96 * wv + 32 * i + col;
            float w[8];
#pragma unroll
            for (int j = 0; j < 8; ++j)
                w[j] = lbuf[(rbase + j) * DD + d];   // conflict-free columns
            short8 b8;
#pragma unroll
            for (int j = 0; j < 8; ++j)
                b8[j] = (short)bf16rne(w[j]);
            acc[i] = __builtin_amdgcn_mfma_f32_32x32x16_bf16(a8, b8, acc[i], 0, 0, 0);
        }
    }

    float* __restrict__ pp = partials + (size_t)c * BL + (size_t)l * DD;
#pragma unroll
    for (int r = 0; r < 16; ++r) {
        int b = (r & 3) + 8 * (r >> 2) + 4 * half;
        float* rowp = pp + (size_t)b * LD + 96 * wv + col;
        rowp[0]  = acc[0][r];
        rowp[32] = acc[1][r];
        rowp[64] = acc[2][r];
    }
}

// Stage 2 (fused): out[o] = bias[ld] + sum_c partials[c][o]
__global__ __launch_bounds__(256) void cc_stage2(
    const float* __restrict__ partials,
    const float* __restrict__ bias,
    float* __restrict__ out)
{
    int o = blockIdx.x * 256 + threadIdx.x;   // 0 .. BL-1
    if (o >= BL) return;
    int b  = o / LD;
    int ld = o - b * LD;
    float s = bias[ld];
    const float* __restrict__ p = partials + o;
#pragma unroll 16
    for (int c = 0; c < NF; ++c, p += BL)
        s += *p;
    out[o] = s;
}

// Correctness-only fallback if workspace is too small (fp32 path).
__global__ __launch_bounds__(256) void cc_direct(
    const float* __restrict__ f,
    const float* __restrict__ weight,
    const float* __restrict__ bias,
    float* __restrict__ out)
{
    int o = blockIdx.x * 256 + threadIdx.x;
    if (o >= BL) return;
    int b  = o / LD;
    int ld = o - b * LD;
    int l  = ld / DD;
    int d  = ld - l * DD;
    float s = bias[ld];
    const float* wp = weight + (size_t)l * FF * DD + d;
    const float* fp = f + (size_t)b * FF;
    for (int fi = 0; fi < FF; ++fi)
        s = fmaf(fp[fi], wp[(size_t)fi * DD], s);
    out[o] = s;
}

extern "C" void kernel_launch(void* const* d_in, const int* in_sizes, int n_in,
                              void* d_out, int out_size, void* d_ws, size_t ws_size,
                              hipStream_t stream)
{
    const float* f      = (const float*)d_in[0];   // 32 x 65536
    const float* weight = (const float*)d_in[1];   // 2 x 65536 x 768
    const float* bias   = (const float*)d_in[2];   // 2 x 768
    float* out          = (float*)d_out;           // 32 x 2 x 768

    const size_t need = APREP_BYTES + (size_t)NF * CHUNK_BYTES;
    if (ws_size < need) {
        cc_direct<<<(BL + 255) / 256, 256, 0, stream>>>(f, weight, bias, out);
        return;
    }

    uint4* aprep    = (uint4*)d_ws;
    float* partials = (float*)((char*)d_ws + APREP_BYTES);

    cc_prep_a<<<(NSTEPS * 64 + 255) / 256, 256, 0, stream>>>(
        (const float4*)f, aprep);

    dim3 grid1(NF, LL);
    cc_mfma<<<grid1, 512, 0, stream>>>(aprep, weight, partials);

    cc_stage2<<<(BL + 255) / 256, 256, 0, stream>>>(partials, bias, out);
}

// Round 22
// 98.105 us; speedup vs baseline: 1.0816x; 1.0816x over previous
//
#include <hip/hip_runtime.h>

// Problem constants: B=32, L=2, F=65536, D=768
#define BB 32
#define LL 2
#define FF 65536
#define DD 768
#define F4 (FF / 4)        // 16384 float4 per f row
#define LD (LL * DD)       // 1536
#define BL (BB * LD)       // 49152 outputs

#define NSTEPS (FF / 16)   // 4096 K16-steps
#define APREP_BYTES ((size_t)NSTEPS * 64 * 16)      // 4 MB
#define CHUNK_BYTES ((size_t)BL * sizeof(float))    // 196608 B
#define NF 128             // F-chunks; grid (NF, 2) = 256 blocks = 1/CU
#define KS (NSTEPS / NF)   // 32 K16-steps per chunk

typedef __attribute__((ext_vector_type(8)))  short short8;   // 8 bf16 (4 VGPR)
typedef __attribute__((ext_vector_type(16))) float float16;  // 16 fp32 acc

// fp32 -> bf16 round-to-nearest-even (finite inputs)
static __device__ __forceinline__ unsigned bf16rne(float x)
{
    unsigned u = __float_as_uint(x);
    return (u + 0x7fffu + ((u >> 16) & 1u)) >> 16;
}
static __device__ __forceinline__ unsigned packbf(float a, float b)
{
    return bf16rne(a) | (bf16rne(b) << 16);
}

// Prep: build A-fragments. aprep[s][lane] (uint4) = 8 bf16 of
// A[row = lane&31][k = s*16 + (lane>>5)*8 + j], j=0..7, A[b][k] = f[b][k].
__global__ __launch_bounds__(256) void cc_prep_a(
    const float4* __restrict__ f4,     // [32][16384]
    uint4* __restrict__ aprep)         // [4096][64]
{
    int t = blockIdx.x * 256 + threadIdx.x;      // 0 .. 4096*64-1
    if (t >= NSTEPS * 64) return;
    int s = t >> 6;
    int l = t & 63;
    int b = l & 31;
    int k0 = s * 16 + ((l >> 5) << 3);           // multiple of 8
    float4 fa = f4[(size_t)b * F4 + (k0 >> 2)];
    float4 fb = f4[(size_t)b * F4 + (k0 >> 2) + 1];
    uint4 u;
    u.x = packbf(fa.x, fa.y);
    u.y = packbf(fa.z, fa.w);
    u.z = packbf(fb.x, fb.y);
    u.w = packbf(fb.z, fb.w);
    aprep[t] = u;
}

// Stage 1: MFMA partial GEMM, linear weight streaming, DOUBLE-BUFFERED LDS.
// grid = (NF, 2); block = 512 (8 waves). Block tile: M=32 x N=768 (full row).
// Per K16-step (ONE barrier):
//   barrier (drains vmcnt -> buf[cur] staged, prev A-frag retired)
//   -> issue 48 global_load_lds dwordx4 (48 KB contiguous) into buf[cur^1]
//   -> prefetch A-frag for s+1 (drained by next barrier: no coupling wait)
//   -> compute step s from buf[cur]: 8 ds_read_b32 column gathers per n-tile
//      (banks = d mod 32, 2 lanes/bank = free) + bf16 cvt + 3x
//      mfma_f32_32x32x16_bf16 per wave.
// HBM stays busy through the compute phase AND the barrier drain (the 48 KB
// in flight IS the next step's data) -> idle only in the ~100cy issue gap.
// R20's serial 2-barrier loop had HBM idle every compute phase (~78% duty).
// LDS 96 KB -> 1 block/CU; VGPR ~85 under (512,2) cap 256 (spill-safe).
// C/D layout (verified): col = lane&31, row = (r&3) + 8*(r>>2) + 4*(lane>>5).
__global__ __launch_bounds__(512, 2) void cc_mfma(
    const uint4* __restrict__ aprep,   // [4096][64]
    const float* __restrict__ weight,  // [2][65536][768]
    float* __restrict__ partials)      // [NF][32][1536]
{
    __shared__ float lbuf[2][16 * DD]; // 2 x 48 KB

    const int tid  = threadIdx.x;
    const int lane = tid & 63;
    const int wv   = tid >> 6;         // 0..7
    const int c    = blockIdx.x;       // 0..NF-1
    const int l    = blockIdx.y;       // 0..1
    const int col  = lane & 31;
    const int half = lane >> 5;

    const float4* __restrict__ wchunk =
        (const float4*)(weight + ((size_t)l * FF + (size_t)c * (KS * 16)) * DD);
    const uint4* __restrict__ ap = aprep + (size_t)c * KS * 64 + lane;

    float16 acc[3];
#pragma unroll
    for (int i = 0; i < 3; ++i)
#pragma unroll
        for (int r = 0; r < 16; ++r) acc[i][r] = 0.f;

    // ---- prologue: A-frag 0, then stage step 0 into buf 0 ----
    uint4 av = ap[0];
    {
        float4* lb4 = (float4*)lbuf[0];
#pragma unroll
        for (int t = 0; t < 6; ++t) {
            int idx = t * 512 + tid;
            __builtin_amdgcn_global_load_lds(
                (const __attribute__((address_space(1))) void*)(wchunk + idx),
                (__attribute__((address_space(3))) void*)(lb4 + idx),
                16, 0, 0);
        }
    }

    int cur = 0;
    for (int s = 0; s < KS; ++s) {
        __syncthreads();   // vmcnt(0): buf[cur] staged, av retired; lgkm done

        uint4 avn = av;
        if (s + 1 < KS) {
            // issue next step's staging into the other buffer
            const float4* __restrict__ gsrc = wchunk + (size_t)(s + 1) * 3072;
            float4* nb4 = (float4*)lbuf[cur ^ 1];
#pragma unroll
            for (int t = 0; t < 6; ++t) {
                int idx = t * 512 + tid;
                __builtin_amdgcn_global_load_lds(
                    (const __attribute__((address_space(1))) void*)(gsrc + idx),
                    (__attribute__((address_space(3))) void*)(nb4 + idx),
                    16, 0, 0);
            }
            avn = ap[(size_t)(s + 1) * 64];   // drained by next barrier
        }

        short8 a8 = __builtin_bit_cast(short8, av);
        const float* __restrict__ lb = lbuf[cur];
        const int rbase = half * 8;
#pragma unroll
        for (int i = 0; i < 3; ++i) {
            const int d = 96 * wv + 32 * i + col;
            float w[8];
#pragma unroll
            for (int j = 0; j < 8; ++j)
                w[j] = lb[(rbase + j) * DD + d];   // 2 lanes/bank: free
            short8 b8;
#pragma unroll
            for (int j = 0; j < 8; ++j)
                b8[j] = (short)bf16rne(w[j]);
            acc[i] = __builtin_amdgcn_mfma_f32_32x32x16_bf16(a8, b8, acc[i], 0, 0, 0);
        }

        av = avn;
        cur ^= 1;
    }

    float* __restrict__ pp = partials + (size_t)c * BL + (size_t)l * DD;
#pragma unroll
    for (int r = 0; r < 16; ++r) {
        int b = (r & 3) + 8 * (r >> 2) + 4 * half;
        float* rowp = pp + (size_t)b * LD + 96 * wv + col;
        rowp[0]  = acc[0][r];
        rowp[32] = acc[1][r];
        rowp[64] = acc[2][r];
    }
}

// Stage 2 (fused): out[o] = bias[ld] + sum_c partials[c][o]
__global__ __launch_bounds__(256) void cc_stage2(
    const float* __restrict__ partials,
    const float* __restrict__ bias,
    float* __restrict__ out)
{
    int o = blockIdx.x * 256 + threadIdx.x;   // 0 .. BL-1
    if (o >= BL) return;
    int b  = o / LD;
    int ld = o - b * LD;
    float s = bias[ld];
    const float* __restrict__ p = partials + o;
#pragma unroll 16
    for (int c = 0; c < NF; ++c, p += BL)
        s += *p;
    out[o] = s;
}

// Correctness-only fallback if workspace is too small (fp32 path).
__global__ __launch_bounds__(256) void cc_direct(
    const float* __restrict__ f,
    const float* __restrict__ weight,
    const float* __restrict__ bias,
    float* __restrict__ out)
{
    int o = blockIdx.x * 256 + threadIdx.x;
    if (o >= BL) return;
    int b  = o / LD;
    int ld = o - b * LD;
    int l  = ld / DD;
    int d  = ld - l * DD;
    float s = bias[ld];
    const float* wp = weight + (size_t)l * FF * DD + d;
    const float* fp = f + (size_t)b * FF;
    for (int fi = 0; fi < FF; ++fi)
        s = fmaf(fp[fi], wp[(size_t)fi * DD], s);
    out[o] = s;
}

extern "C" void kernel_launch(void* const* d_in, const int* in_sizes, int n_in,
                              void* d_out, int out_size, void* d_ws, size_t ws_size,
                              hipStream_t stream)
{
    const float* f      = (const float*)d_in[0];   // 32 x 65536
    const float* weight = (const float*)d_in[1];   // 2 x 65536 x 768
    const float* bias   = (const float*)d_in[2];   // 2 x 768
    float* out          = (float*)d_out;           // 32 x 2 x 768

    const size_t need = APREP_BYTES + (size_t)NF * CHUNK_BYTES;
    if (ws_size < need) {
        cc_direct<<<(BL + 255) / 256, 256, 0, stream>>>(f, weight, bias, out);
        return;
    }

    uint4* aprep    = (uint4*)d_ws;
    float* partials = (float*)((char*)d_ws + APREP_BYTES);

    cc_prep_a<<<(NSTEPS * 64 + 255) / 256, 256, 0, stream>>>(
        (const float4*)f, aprep);

    dim3 grid1(NF, LL);
    cc_mfma<<<grid1, 512, 0, stream>>>(aprep, weight, partials);

    cc_stage2<<<(BL + 255) / 256, 256, 0, stream>>>(partials, bias, out);
}

// Round 23
// 92.332 us; speedup vs baseline: 1.1493x; 1.0625x over previous
//
#include <hip/hip_runtime.h>

// Problem constants: B=32, L=2, F=65536, D=768
#define BB 32
#define LL 2
#define FF 65536
#define DD 768
#define F4 (FF / 4)        // 16384 float4 per f row
#define LD (LL * DD)       // 1536
#define BL (BB * LD)       // 49152 outputs

#define NSTEPS (FF / 16)   // 4096 K16-steps
#define CHUNK_BYTES ((size_t)BL * sizeof(float))    // 196608 B
#define NF 128             // F-chunks; grid (NF, 2) = 256 blocks = 1/CU
#define KS (NSTEPS / NF)   // 32 K16-steps per chunk

typedef __attribute__((ext_vector_type(8)))  short short8;   // 8 bf16 (4 VGPR)
typedef __attribute__((ext_vector_type(16))) float float16;  // 16 fp32 acc

// fp32 -> bf16 round-to-nearest-even (finite inputs)
static __device__ __forceinline__ unsigned bf16rne(float x)
{
    unsigned u = __float_as_uint(x);
    return (u + 0x7fffu + ((u >> 16) & 1u)) >> 16;
}

// Stage 1: MFMA partial GEMM, linear weight streaming, double-buffered LDS,
// A-fragments built IN-KERNEL from f (no prep kernel, no aprep round-trip).
// grid = (NF, 2); block = 512 (8 waves). Block tile: M=32 x N=768 (full row).
// Per K16-step (one barrier):
//   barrier (vmcnt(0): buf[cur] staged, this step's f-regs retired)
//   -> issue 48 global_load_lds dwordx4 (48 KB contiguous) into buf[cur^1]
//   -> prefetch next step's 2 f float4s (row lane&31; 64 KB/block total,
//      L2/L3-resident) — drained by the next barrier, never waited on here
//   -> build a8 (8 bf16 cvts) + compute 3 n-tiles from buf[cur]:
//      8 ds_read_b32 column gathers (banks = d mod 32, 2 lanes/bank = free)
//      + bf16 cvt + mfma_f32_32x32x16_bf16.
// A-fragment mapping (verified m74/m101): A row = lane&31,
// k = s*16 + (lane>>5)*8 + j; C/D col = lane&31, row = (r&3)+8*(r>>2)+4*half.
// LDS 96 KB -> 1 block/CU; VGPR ~110 under (512,2) cap 256 (spill-safe).
__global__ __launch_bounds__(512, 2) void cc_mfma(
    const float4* __restrict__ f4,     // [32][16384]
    const float* __restrict__ weight,  // [2][65536][768]
    float* __restrict__ partials)      // [NF][32][1536]
{
    __shared__ float lbuf[2][16 * DD]; // 2 x 48 KB

    const int tid  = threadIdx.x;
    const int lane = tid & 63;
    const int wv   = tid >> 6;         // 0..7
    const int c    = blockIdx.x;       // 0..NF-1
    const int l    = blockIdx.y;       // 0..1
    const int col  = lane & 31;
    const int half = lane >> 5;

    const float4* __restrict__ wchunk =
        (const float4*)(weight + ((size_t)l * FF + (size_t)c * (KS * 16)) * DD);

    // lane's f stream: row b = col, column base c*KS*16 + half*8 (in float4s)
    const float4* __restrict__ fbase =
        f4 + (size_t)col * F4 + (size_t)c * KS * 4 + half * 2;

    float16 acc[3];
#pragma unroll
    for (int i = 0; i < 3; ++i)
#pragma unroll
        for (int r = 0; r < 16; ++r) acc[i][r] = 0.f;

    // ---- prologue: f-frag 0 + stage step 0 into buf 0 ----
    float4 fv0 = fbase[0];
    float4 fv1 = fbase[1];
    {
        float4* lb4 = (float4*)lbuf[0];
#pragma unroll
        for (int t = 0; t < 6; ++t) {
            int idx = t * 512 + tid;
            __builtin_amdgcn_global_load_lds(
                (const __attribute__((address_space(1))) void*)(wchunk + idx),
                (__attribute__((address_space(3))) void*)(lb4 + idx),
                16, 0, 0);
        }
    }

    int cur = 0;
    for (int s = 0; s < KS; ++s) {
        __syncthreads();   // vmcnt(0): buf[cur] staged, fv0/fv1 retired

        float4 nf0 = fv0, nf1 = fv1;
        if (s + 1 < KS) {
            // issue next step's staging into the other buffer
            const float4* __restrict__ gsrc = wchunk + (size_t)(s + 1) * 3072;
            float4* nb4 = (float4*)lbuf[cur ^ 1];
#pragma unroll
            for (int t = 0; t < 6; ++t) {
                int idx = t * 512 + tid;
                __builtin_amdgcn_global_load_lds(
                    (const __attribute__((address_space(1))) void*)(gsrc + idx),
                    (__attribute__((address_space(3))) void*)(nb4 + idx),
                    16, 0, 0);
            }
            nf0 = fbase[(size_t)(s + 1) * 4];       // drained by next barrier
            nf1 = fbase[(size_t)(s + 1) * 4 + 1];
        }

        // build A-fragment: a8[j] = bf16(f[col][k0+j])
        short8 a8;
        a8[0] = (short)bf16rne(fv0.x);
        a8[1] = (short)bf16rne(fv0.y);
        a8[2] = (short)bf16rne(fv0.z);
        a8[3] = (short)bf16rne(fv0.w);
        a8[4] = (short)bf16rne(fv1.x);
        a8[5] = (short)bf16rne(fv1.y);
        a8[6] = (short)bf16rne(fv1.z);
        a8[7] = (short)bf16rne(fv1.w);

        const float* __restrict__ lb = lbuf[cur];
        const int rbase = half * 8;
#pragma unroll
        for (int i = 0; i < 3; ++i) {
            const int d = 96 * wv + 32 * i + col;
            float w[8];
#pragma unroll
            for (int j = 0; j < 8; ++j)
                w[j] = lb[(rbase + j) * DD + d];   // 2 lanes/bank: free
            short8 b8;
#pragma unroll
            for (int j = 0; j < 8; ++j)
                b8[j] = (short)bf16rne(w[j]);
            acc[i] = __builtin_amdgcn_mfma_f32_32x32x16_bf16(a8, b8, acc[i], 0, 0, 0);
        }

        fv0 = nf0; fv1 = nf1;
        cur ^= 1;
    }

    float* __restrict__ pp = partials + (size_t)c * BL + (size_t)l * DD;
#pragma unroll
    for (int r = 0; r < 16; ++r) {
        int b = (r & 3) + 8 * (r >> 2) + 4 * half;
        float* rowp = pp + (size_t)b * LD + 96 * wv + col;
        rowp[0]  = acc[0][r];
        rowp[32] = acc[1][r];
        rowp[64] = acc[2][r];
    }
}

// Stage 2 (fused): out[o] = bias[ld] + sum_c partials[c][o]
__global__ __launch_bounds__(256) void cc_stage2(
    const float* __restrict__ partials,
    const float* __restrict__ bias,
    float* __restrict__ out)
{
    int o = blockIdx.x * 256 + threadIdx.x;   // 0 .. BL-1
    if (o >= BL) return;
    int b  = o / LD;
    int ld = o - b * LD;
    float s = bias[ld];
    const float* __restrict__ p = partials + o;
#pragma unroll 16
    for (int c = 0; c < NF; ++c, p += BL)
        s += *p;
    out[o] = s;
}

// Correctness-only fallback if workspace is too small (fp32 path).
__global__ __launch_bounds__(256) void cc_direct(
    const float* __restrict__ f,
    const float* __restrict__ weight,
    const float* __restrict__ bias,
    float* __restrict__ out)
{
    int o = blockIdx.x * 256 + threadIdx.x;
    if (o >= BL) return;
    int b  = o / LD;
    int ld = o - b * LD;
    int l  = ld / DD;
    int d  = ld - l * DD;
    float s = bias[ld];
    const float* wp = weight + (size_t)l * FF * DD + d;
    const float* fp = f + (size_t)b * FF;
    for (int fi = 0; fi < FF; ++fi)
        s = fmaf(fp[fi], wp[(size_t)fi * DD], s);
    out[o] = s;
}

extern "C" void kernel_launch(void* const* d_in, const int* in_sizes, int n_in,
                              void* d_out, int out_size, void* d_ws, size_t ws_size,
                              hipStream_t stream)
{
    const float* f      = (const float*)d_in[0];   // 32 x 65536
    const float* weight = (const float*)d_in[1];   // 2 x 65536 x 768
    const float* bias   = (const float*)d_in[2];   // 2 x 768
    float* out          = (float*)d_out;           // 32 x 2 x 768

    const size_t need = (size_t)NF * CHUNK_BYTES;
    if (ws_size < need) {
        cc_direct<<<(BL + 255) / 256, 256, 0, stream>>>(f, weight, bias, out);
        return;
    }

    float* partials = (float*)d_ws;

    dim3 grid1(NF, LL);
    cc_mfma<<<grid1, 512, 0, stream>>>((const float4*)f, weight, partials);

    cc_stage2<<<(BL + 255) / 256, 256, 0, stream>>>(partials, bias, out);
}

// Round 24
// 92.208 us; speedup vs baseline: 1.1508x; 1.0013x over previous
//
#include <hip/hip_runtime.h>

// Problem constants: B=32, L=2, F=65536, D=768
#define BB 32
#define LL 2
#define FF 65536
#define DD 768
#define F4 (FF / 4)        // 16384 float4 per f row
#define LD (LL * DD)       // 1536
#define BL (BB * LD)       // 49152 outputs

#define NSTEPS (FF / 16)   // 4096 K16-steps
#define CHUNK_BYTES ((size_t)BL * sizeof(float))    // 196608 B
#define NF 128             // F-chunks; grid (NF, 2) = 256 blocks = 1/CU
#define KS (NSTEPS / NF)   // 32 K16-steps per chunk

typedef __attribute__((ext_vector_type(8)))  short short8;   // 8 bf16 (4 VGPR)
typedef __attribute__((ext_vector_type(16))) float float16;  // 16 fp32 acc

// fp32 -> bf16 round-to-nearest-even (finite inputs)
static __device__ __forceinline__ unsigned bf16rne(float x)
{
    unsigned u = __float_as_uint(x);
    return (u + 0x7fffu + ((u >> 16) & 1u)) >> 16;
}

// Stage 1: MFMA partial GEMM, linear weight streaming, TRIPLE-buffered LDS
// with counted vmcnt (T3/T4): the vmem queue is never drained to 0 in the
// main loop, so HBM always has >= 1 full 48 KB stage group in flight.
// grid = (NF, 2); block = 512 (8 waves). Block tile: M=32 x N=768.
// Per wave per K16-step: exactly 8 vmem ops = 6 global_load_lds dwordx4
// (48 KB contiguous block-wide) + 2 f float4 loads. Steady-state loop:
//   s_waitcnt vmcnt(8)   // retire group s; group s+1 still flying
//   s_barrier (raw)      // all waves' group-s writes landed; no drain
//   issue group s+2      // into the buffer compute(s-1) released
//   compute s            // ds_read column gathers + bf16 cvt + MFMA
// vmcnt(0) only at s = KS-1 (R22's 2-buffer loop drained to 0 EVERY step ->
// per-step issue gap with zero bytes in flight; m233: that drain IS the
// 2-phase critical path).  Unrolled x3 so buffer/f-reg indices are static.
// A-frag (verified): row = lane&31, k = s*16 + (lane>>5)*8 + j.
// C/D (verified): col = lane&31, row b = (r&3) + 8*(r>>2) + 4*(lane>>5).
// LDS 144 KB -> 1 block/CU; VGPR ~115 under (512,2) cap 256 (spill-safe).
__global__ __launch_bounds__(512, 2) void cc_mfma(
    const float4* __restrict__ f4,     // [32][16384]
    const float* __restrict__ weight,  // [2][65536][768]
    float* __restrict__ partials)      // [NF][32][1536]
{
    __shared__ float lbuf[3][16 * DD]; // 3 x 48 KB = 144 KB

    const int tid  = threadIdx.x;
    const int lane = tid & 63;
    const int wv   = tid >> 6;         // 0..7
    const int c    = blockIdx.x;       // 0..NF-1
    const int l    = blockIdx.y;       // 0..1
    const int col  = lane & 31;
    const int half = lane >> 5;

    const float4* __restrict__ wchunk =
        (const float4*)(weight + ((size_t)l * FF + (size_t)c * (KS * 16)) * DD);
    // lane's f stream: row b = col, float4 index c*KS*4 + s*4 + half*2
    const float4* __restrict__ fbase =
        f4 + (size_t)col * F4 + (size_t)c * KS * 4 + half * 2;

    float16 acc[3];
#pragma unroll
    for (int i = 0; i < 3; ++i)
#pragma unroll
        for (int r = 0; r < 16; ++r) acc[i][r] = 0.f;

#define FENCE() asm volatile("" ::: "memory")

#define ISSUE_STAGE(BIDX, SIDX)                                               \
    do {                                                                      \
        const float4* gsrc_ = wchunk + (size_t)(SIDX) * 3072;                 \
        float4* nb4_ = (float4*)lbuf[(BIDX)];                                 \
        _Pragma("unroll")                                                     \
        for (int t_ = 0; t_ < 6; ++t_) {                                      \
            int idx_ = t_ * 512 + tid;                                        \
            __builtin_amdgcn_global_load_lds(                                 \
                (const __attribute__((address_space(1))) void*)(gsrc_ + idx_),\
                (__attribute__((address_space(3))) void*)(nb4_ + idx_),       \
                16, 0, 0);                                                    \
        }                                                                     \
    } while (0)

#define COMPUTE(BIDX, FX0, FX1)                                               \
    do {                                                                      \
        short8 a8_;                                                           \
        a8_[0] = (short)bf16rne((FX0).x);                                     \
        a8_[1] = (short)bf16rne((FX0).y);                                     \
        a8_[2] = (short)bf16rne((FX0).z);                                     \
        a8_[3] = (short)bf16rne((FX0).w);                                     \
        a8_[4] = (short)bf16rne((FX1).x);                                     \
        a8_[5] = (short)bf16rne((FX1).y);                                     \
        a8_[6] = (short)bf16rne((FX1).z);                                     \
        a8_[7] = (short)bf16rne((FX1).w);                                     \
        const float* lb_ = lbuf[(BIDX)];                                      \
        const int rbase_ = half * 8;                                          \
        _Pragma("unroll")                                                     \
        for (int i_ = 0; i_ < 3; ++i_) {                                      \
            const int d_ = 96 * wv + 32 * i_ + col;                           \
            float w_[8];                                                      \
            _Pragma("unroll")                                                 \
            for (int j_ = 0; j_ < 8; ++j_)                                    \
                w_[j_] = lb_[(rbase_ + j_) * DD + d_];  /* 2 lanes/bank */    \
            short8 b8_;                                                       \
            _Pragma("unroll")                                                 \
            for (int j_ = 0; j_ < 8; ++j_)                                    \
                b8_[j_] = (short)bf16rne(w_[j_]);                             \
            acc[i_] = __builtin_amdgcn_mfma_f32_32x32x16_bf16(                \
                a8_, b8_, acc[i_], 0, 0, 0);                                  \
        }                                                                     \
    } while (0)

// One K16-step: counted wait, raw barrier, issue 2-ahead, compute current.
#define SUBITER(S, BIDX, FX0, FX1, NBIDX, NF0, NF1)                           \
    do {                                                                      \
        if ((S) == KS - 1) asm volatile("s_waitcnt vmcnt(0)" ::: "memory");   \
        else               asm volatile("s_waitcnt vmcnt(8)" ::: "memory");   \
        asm volatile("s_barrier" ::: "memory");                               \
        if ((S) + 2 < KS) {                                                   \
            ISSUE_STAGE(NBIDX, (S) + 2);                                      \
            NF0 = fbase[(size_t)((S) + 2) * 4];                               \
            NF1 = fbase[(size_t)((S) + 2) * 4 + 1];                           \
            FENCE();                                                          \
        }                                                                     \
        COMPUTE(BIDX, FX0, FX1);                                              \
    } while (0)

    float4 fA0, fA1, fB0, fB1, fC0, fC1;
    fC0 = make_float4(0.f, 0.f, 0.f, 0.f);
    fC1 = fC0;

    // prologue: groups 0 and 1 (group order pinned by fences)
    ISSUE_STAGE(0, 0);
    fA0 = fbase[0]; fA1 = fbase[1];
    FENCE();
    ISSUE_STAGE(1, 1);
    fB0 = fbase[4]; fB1 = fbase[5];
    FENCE();

    for (int st = 0; st < KS; st += 3) {
        SUBITER(st, 0, fA0, fA1, 2, fC0, fC1);
        if (st + 1 < KS) SUBITER(st + 1, 1, fB0, fB1, 0, fA0, fA1);
        if (st + 2 < KS) SUBITER(st + 2, 2, fC0, fC1, 1, fB0, fB1);
    }

    float* __restrict__ pp = partials + (size_t)c * BL + (size_t)l * DD;
#pragma unroll
    for (int r = 0; r < 16; ++r) {
        int b = (r & 3) + 8 * (r >> 2) + 4 * half;
        float* rowp = pp + (size_t)b * LD + 96 * wv + col;
        rowp[0]  = acc[0][r];
        rowp[32] = acc[1][r];
        rowp[64] = acc[2][r];
    }
}

// Stage 2 (fused): out[o] = bias[ld] + sum_c partials[c][o]
__global__ __launch_bounds__(256) void cc_stage2(
    const float* __restrict__ partials,
    const float* __restrict__ bias,
    float* __restrict__ out)
{
    int o = blockIdx.x * 256 + threadIdx.x;   // 0 .. BL-1
    if (o >= BL) return;
    int b  = o / LD;
    int ld = o - b * LD;
    float s = bias[ld];
    const float* __restrict__ p = partials + o;
#pragma unroll 16
    for (int c = 0; c < NF; ++c, p += BL)
        s += *p;
    out[o] = s;
}

// Correctness-only fallback if workspace is too small (fp32 path).
__global__ __launch_bounds__(256) void cc_direct(
    const float* __restrict__ f,
    const float* __restrict__ weight,
    const float* __restrict__ bias,
    float* __restrict__ out)
{
    int o = blockIdx.x * 256 + threadIdx.x;
    if (o >= BL) return;
    int b  = o / LD;
    int ld = o - b * LD;
    int l  = ld / DD;
    int d  = ld - l * DD;
    float s = bias[ld];
    const float* wp = weight + (size_t)l * FF * DD + d;
    const float* fp = f + (size_t)b * FF;
    for (int fi = 0; fi < FF; ++fi)
        s = fmaf(fp[fi], wp[(size_t)fi * DD], s);
    out[o] = s;
}

extern "C" void kernel_launch(void* const* d_in, const int* in_sizes, int n_in,
                              void* d_out, int out_size, void* d_ws, size_t ws_size,
                              hipStream_t stream)
{
    const float* f      = (const float*)d_in[0];   // 32 x 65536
    const float* weight = (const float*)d_in[1];   // 2 x 65536 x 768
    const float* bias   = (const float*)d_in[2];   // 2 x 768
    float* out          = (float*)d_out;           // 32 x 2 x 768

    const size_t need = (size_t)NF * CHUNK_BYTES;
    if (ws_size < need) {
        cc_direct<<<(BL + 255) / 256, 256, 0, stream>>>(f, weight, bias, out);
        return;
    }

    float* partials = (float*)d_ws;

    dim3 grid1(NF, LL);
    cc_mfma<<<grid1, 512, 0, stream>>>((const float4*)f, weight, partials);

    cc_stage2<<<(BL + 255) / 256, 256, 0, stream>>>(partials, bias, out);
}

// Round 25
// 87.715 us; speedup vs baseline: 1.2097x; 1.0512x over previous
//
#include <hip/hip_runtime.h>

// Problem constants: B=32, L=2, F=65536, D=768
#define BB 32
#define LL 2
#define FF 65536
#define DD 768
#define F4 (FF / 4)        // 16384 float4 per f row
#define LD (LL * DD)       // 1536
#define BL (BB * LD)       // 49152 outputs

#define NSTEPS (FF / 16)   // 4096 K16-steps
#define NF 128             // F-chunks; grid (NF, 2) = 256 blocks = 1/CU
#define KS (NSTEPS / NF)   // 32 K16-steps per chunk

// bf16-packed partials: per (c,l) chunk, 24 uint slots x 512 threads.
// slot j = i*8+rp holds pack(acc[i][2rp], acc[i][2rp+1]) for thread tid.
#define PCHUNK 12288                        // uints per (c,l) chunk (24*512)
#define PART_BYTES ((size_t)NF * 2 * PCHUNK * 4)   // 12.58 MB

typedef __attribute__((ext_vector_type(8)))  short short8;   // 8 bf16 (4 VGPR)
typedef __attribute__((ext_vector_type(16))) float float16;  // 16 fp32 acc

// fp32 -> bf16 round-to-nearest-even (finite inputs)
static __device__ __forceinline__ unsigned bf16rne(float x)
{
    unsigned u = __float_as_uint(x);
    return (u + 0x7fffu + ((u >> 16) & 1u)) >> 16;
}

// Stage 1: MFMA partial GEMM, linear weight streaming, triple-buffered LDS
// with counted vmcnt (structure identical to R24 == best). Epilogue writes
// bf16-PACKED partials in MFMA-native lane-major order: 24 uint stores/lane,
// each slot 2 KB contiguous block-wide (halves partials traffic; stage-2
// applies the known index permutation).
// grid = (NF, 2); block = 512 (8 waves). Block tile: M=32 x N=768.
// A-frag (verified): row = lane&31, k = s*16 + (lane>>5)*8 + j.
// C/D (verified): col = lane&31, row b = (r&3) + 8*(r>>2) + 4*(lane>>5).
// LDS 144 KB -> 1 block/CU; VGPR ~115 under (512,2) cap 256 (spill-safe).
__global__ __launch_bounds__(512, 2) void cc_mfma(
    const float4* __restrict__ f4,     // [32][16384]
    const float* __restrict__ weight,  // [2][65536][768]
    unsigned* __restrict__ partials)   // [NF*2][PCHUNK] bf16-packed
{
    __shared__ float lbuf[3][16 * DD]; // 3 x 48 KB = 144 KB

    const int tid  = threadIdx.x;
    const int lane = tid & 63;
    const int wv   = tid >> 6;         // 0..7
    const int c    = blockIdx.x;       // 0..NF-1
    const int l    = blockIdx.y;       // 0..1
    const int col  = lane & 31;
    const int half = lane >> 5;

    const float4* __restrict__ wchunk =
        (const float4*)(weight + ((size_t)l * FF + (size_t)c * (KS * 16)) * DD);
    // lane's f stream: row b = col, float4 index c*KS*4 + s*4 + half*2
    const float4* __restrict__ fbase =
        f4 + (size_t)col * F4 + (size_t)c * KS * 4 + half * 2;

    float16 acc[3];
#pragma unroll
    for (int i = 0; i < 3; ++i)
#pragma unroll
        for (int r = 0; r < 16; ++r) acc[i][r] = 0.f;

#define FENCE() asm volatile("" ::: "memory")

#define ISSUE_STAGE(BIDX, SIDX)                                               \
    do {                                                                      \
        const float4* gsrc_ = wchunk + (size_t)(SIDX) * 3072;                 \
        float4* nb4_ = (float4*)lbuf[(BIDX)];                                 \
        _Pragma("unroll")                                                     \
        for (int t_ = 0; t_ < 6; ++t_) {                                      \
            int idx_ = t_ * 512 + tid;                                        \
            __builtin_amdgcn_global_load_lds(                                 \
                (const __attribute__((address_space(1))) void*)(gsrc_ + idx_),\
                (__attribute__((address_space(3))) void*)(nb4_ + idx_),       \
                16, 0, 0);                                                    \
        }                                                                     \
    } while (0)

#define COMPUTE(BIDX, FX0, FX1)                                               \
    do {                                                                      \
        short8 a8_;                                                           \
        a8_[0] = (short)bf16rne((FX0).x);                                     \
        a8_[1] = (short)bf16rne((FX0).y);                                     \
        a8_[2] = (short)bf16rne((FX0).z);                                     \
        a8_[3] = (short)bf16rne((FX0).w);                                     \
        a8_[4] = (short)bf16rne((FX1).x);                                     \
        a8_[5] = (short)bf16rne((FX1).y);                                     \
        a8_[6] = (short)bf16rne((FX1).z);                                     \
        a8_[7] = (short)bf16rne((FX1).w);                                     \
        const float* lb_ = lbuf[(BIDX)];                                      \
        const int rbase_ = half * 8;                                          \
        _Pragma("unroll")                                                     \
        for (int i_ = 0; i_ < 3; ++i_) {                                      \
            const int d_ = 96 * wv + 32 * i_ + col;                           \
            float w_[8];                                                      \
            _Pragma("unroll")                                                 \
            for (int j_ = 0; j_ < 8; ++j_)                                    \
                w_[j_] = lb_[(rbase_ + j_) * DD + d_];  /* 2 lanes/bank */    \
            short8 b8_;                                                       \
            _Pragma("unroll")                                                 \
            for (int j_ = 0; j_ < 8; ++j_)                                    \
                b8_[j_] = (short)bf16rne(w_[j_]);                             \
            acc[i_] = __builtin_amdgcn_mfma_f32_32x32x16_bf16(                \
                a8_, b8_, acc[i_], 0, 0, 0);                                  \
        }                                                                     \
    } while (0)

#define SUBITER(S, BIDX, FX0, FX1, NBIDX, NF0, NF1)                           \
    do {                                                                      \
        if ((S) == KS - 1) asm volatile("s_waitcnt vmcnt(0)" ::: "memory");   \
        else               asm volatile("s_waitcnt vmcnt(8)" ::: "memory");   \
        asm volatile("s_barrier" ::: "memory");                               \
        if ((S) + 2 < KS) {                                                   \
            ISSUE_STAGE(NBIDX, (S) + 2);                                      \
            NF0 = fbase[(size_t)((S) + 2) * 4];                               \
            NF1 = fbase[(size_t)((S) + 2) * 4 + 1];                           \
            FENCE();                                                          \
        }                                                                     \
        COMPUTE(BIDX, FX0, FX1);                                              \
    } while (0)

    float4 fA0, fA1, fB0, fB1, fC0, fC1;
    fC0 = make_float4(0.f, 0.f, 0.f, 0.f);
    fC1 = fC0;

    // prologue: groups 0 and 1 (group order pinned by fences)
    ISSUE_STAGE(0, 0);
    fA0 = fbase[0]; fA1 = fbase[1];
    FENCE();
    ISSUE_STAGE(1, 1);
    fB0 = fbase[4]; fB1 = fbase[5];
    FENCE();

    for (int st = 0; st < KS; st += 3) {
        SUBITER(st, 0, fA0, fA1, 2, fC0, fC1);
        if (st + 1 < KS) SUBITER(st + 1, 1, fB0, fB1, 0, fA0, fA1);
        if (st + 2 < KS) SUBITER(st + 2, 2, fC0, fC1, 1, fB0, fB1);
    }

    // epilogue: bf16-packed, lane-major (slot j = i*8+rp -> 2KB contiguous)
    unsigned* __restrict__ pp = partials + (size_t)(c * 2 + l) * PCHUNK;
#pragma unroll
    for (int i = 0; i < 3; ++i)
#pragma unroll
        for (int rp = 0; rp < 8; ++rp) {
            unsigned u = bf16rne(acc[i][2 * rp]) |
                         (bf16rne(acc[i][2 * rp + 1]) << 16);
            pp[(i * 8 + rp) * 512 + tid] = u;
        }
}

// Stage 2: unpack + reduce + bias. 24576 positions x 2 bf16 values each.
// Thread t: l = t/PCHUNK, rem = t%PCHUNK, j = rem>>9, tid = rem&511.
// Reads stride 2*PCHUNK uints per c (coalesced across consecutive t).
__global__ __launch_bounds__(256) void cc_stage2(
    const unsigned* __restrict__ partials,
    const float* __restrict__ bias,
    float* __restrict__ out)
{
    int t = blockIdx.x * 256 + threadIdx.x;   // 0 .. 24575
    if (t >= 2 * PCHUNK) return;
    int l   = t / PCHUNK;
    int rem = t - l * PCHUNK;
    int j   = rem >> 9;          // 0..23
    int tid = rem & 511;
    int wv = tid >> 6, lane = tid & 63, col = lane & 31, half = lane >> 5;
    int i = j >> 3, rp = j & 7;
    int r0 = 2 * rp, r1 = 2 * rp + 1;

    float s0 = 0.f, s1 = 0.f;
    const unsigned* __restrict__ p = partials + (size_t)l * PCHUNK + rem;
#pragma unroll 16
    for (int c = 0; c < NF; ++c, p += 2 * PCHUNK) {
        unsigned u = *p;
        s0 += __uint_as_float(u << 16);
        s1 += __uint_as_float(u & 0xffff0000u);
    }

    int d  = 96 * wv + 32 * i + col;
    int ld = l * DD + d;
    int b0 = (r0 & 3) + 8 * (r0 >> 2) + 4 * half;
    int b1 = (r1 & 3) + 8 * (r1 >> 2) + 4 * half;
    float bs = bias[ld];
    out[(size_t)b0 * LD + ld] = bs + s0;
    out[(size_t)b1 * LD + ld] = bs + s1;
}

// Correctness-only fallback if workspace is too small (fp32 path).
__global__ __launch_bounds__(256) void cc_direct(
    const float* __restrict__ f,
    const float* __restrict__ weight,
    const float* __restrict__ bias,
    float* __restrict__ out)
{
    int o = blockIdx.x * 256 + threadIdx.x;
    if (o >= BL) return;
    int b  = o / LD;
    int ld = o - b * LD;
    int l  = ld / DD;
    int d  = ld - l * DD;
    float s = bias[ld];
    const float* wp = weight + (size_t)l * FF * DD + d;
    const float* fp = f + (size_t)b * FF;
    for (int fi = 0; fi < FF; ++fi)
        s = fmaf(fp[fi], wp[(size_t)fi * DD], s);
    out[o] = s;
}

extern "C" void kernel_launch(void* const* d_in, const int* in_sizes, int n_in,
                              void* d_out, int out_size, void* d_ws, size_t ws_size,
                              hipStream_t stream)
{
    const float* f      = (const float*)d_in[0];   // 32 x 65536
    const float* weight = (const float*)d_in[1];   // 2 x 65536 x 768
    const float* bias   = (const float*)d_in[2];   // 2 x 768
    float* out          = (float*)d_out;           // 32 x 2 x 768

    if (ws_size < PART_BYTES) {
        cc_direct<<<(BL + 255) / 256, 256, 0, stream>>>(f, weight, bias, out);
        return;
    }

    unsigned* partials = (unsigned*)d_ws;

    dim3 grid1(NF, LL);
    cc_mfma<<<grid1, 512, 0, stream>>>((const float4*)f, weight, partials);

    cc_stage2<<<(2 * PCHUNK + 255) / 256, 256, 0, stream>>>(
        partials, bias, out);
}

// Round 26
// 78.869 us; speedup vs baseline: 1.3454x; 1.1122x over previous
//
#include <hip/hip_runtime.h>

// Problem constants: B=32, L=2, F=65536, D=768
#define BB 32
#define LL 2
#define FF 65536
#define DD 768
#define F4 (FF / 4)        // 16384 float4 per f row
#define LD (LL * DD)       // 1536
#define BL (BB * LD)       // 49152 outputs

#define NSTEPS (FF / 16)   // 4096 K16-steps
#define NF 128             // F-chunks; grid (NF, 2) = 256 blocks = 1/CU
#define KS (NSTEPS / NF)   // 32 K16-steps per chunk

// bf16-packed partials: per (c,l) chunk, 24 uint slots x 512 threads.
#define PCHUNK 12288                        // uints per (c,l) chunk (24*512)
#define PART_BYTES ((size_t)NF * 2 * PCHUNK * 4)   // 12.58 MB

typedef __attribute__((ext_vector_type(8)))  short short8;   // 8 bf16 (4 VGPR)
typedef __attribute__((ext_vector_type(16))) float float16;  // 16 fp32 acc

// fp32 -> bf16 round-to-nearest-even (finite inputs)
static __device__ __forceinline__ unsigned bf16rne(float x)
{
    unsigned u = __float_as_uint(x);
    return (u + 0x7fffu + ((u >> 16) & 1u)) >> 16;
}

// Stage 1: MFMA partial GEMM, linear weight streaming, triple-buffered LDS,
// counted vmcnt (R24/R25 structure). Single change vs R25: weight
// global_load_lds carries aux=2 = NT (non-temporal) cache policy — the
// 402 MB stream is single-use, so skip L2 retention (gfx940+ CPol: NT=bit1).
// grid = (NF, 2); block = 512 (8 waves). Block tile: M=32 x N=768.
// A-frag (verified): row = lane&31, k = s*16 + (lane>>5)*8 + j.
// C/D (verified): col = lane&31, row b = (r&3) + 8*(r>>2) + 4*(lane>>5).
// LDS 144 KB -> 1 block/CU; VGPR ~115 under (512,2) cap 256 (spill-safe).
__global__ __launch_bounds__(512, 2) void cc_mfma(
    const float4* __restrict__ f4,     // [32][16384]
    const float* __restrict__ weight,  // [2][65536][768]
    unsigned* __restrict__ partials)   // [NF*2][PCHUNK] bf16-packed
{
    __shared__ float lbuf[3][16 * DD]; // 3 x 48 KB = 144 KB

    const int tid  = threadIdx.x;
    const int lane = tid & 63;
    const int wv   = tid >> 6;         // 0..7
    const int c    = blockIdx.x;       // 0..NF-1
    const int l    = blockIdx.y;       // 0..1
    const int col  = lane & 31;
    const int half = lane >> 5;

    const float4* __restrict__ wchunk =
        (const float4*)(weight + ((size_t)l * FF + (size_t)c * (KS * 16)) * DD);
    // lane's f stream: row b = col, float4 index c*KS*4 + s*4 + half*2
    const float4* __restrict__ fbase =
        f4 + (size_t)col * F4 + (size_t)c * KS * 4 + half * 2;

    float16 acc[3];
#pragma unroll
    for (int i = 0; i < 3; ++i)
#pragma unroll
        for (int r = 0; r < 16; ++r) acc[i][r] = 0.f;

#define FENCE() asm volatile("" ::: "memory")

#define ISSUE_STAGE(BIDX, SIDX)                                               \
    do {                                                                      \
        const float4* gsrc_ = wchunk + (size_t)(SIDX) * 3072;                 \
        float4* nb4_ = (float4*)lbuf[(BIDX)];                                 \
        _Pragma("unroll")                                                     \
        for (int t_ = 0; t_ < 6; ++t_) {                                      \
            int idx_ = t_ * 512 + tid;                                        \
            __builtin_amdgcn_global_load_lds(                                 \
                (const __attribute__((address_space(1))) void*)(gsrc_ + idx_),\
                (__attribute__((address_space(3))) void*)(nb4_ + idx_),       \
                16, 0, 2 /* NT: single-use stream, no L2 retention */);       \
        }                                                                     \
    } while (0)

#define COMPUTE(BIDX, FX0, FX1)                                               \
    do {                                                                      \
        short8 a8_;                                                           \
        a8_[0] = (short)bf16rne((FX0).x);                                     \
        a8_[1] = (short)bf16rne((FX0).y);                                     \
        a8_[2] = (short)bf16rne((FX0).z);                                     \
        a8_[3] = (short)bf16rne((FX0).w);                                     \
        a8_[4] = (short)bf16rne((FX1).x);                                     \
        a8_[5] = (short)bf16rne((FX1).y);                                     \
        a8_[6] = (short)bf16rne((FX1).z);                                     \
        a8_[7] = (short)bf16rne((FX1).w);                                     \
        const float* lb_ = lbuf[(BIDX)];                                      \
        const int rbase_ = half * 8;                                          \
        _Pragma("unroll")                                                     \
        for (int i_ = 0; i_ < 3; ++i_) {                                      \
            const int d_ = 96 * wv + 32 * i_ + col;                           \
            float w_[8];                                                      \
            _Pragma("unroll")                                                 \
            for (int j_ = 0; j_ < 8; ++j_)                                    \
                w_[j_] = lb_[(rbase_ + j_) * DD + d_];  /* 2 lanes/bank */    \
            short8 b8_;                                                       \
            _Pragma("unroll")                                                 \
            for (int j_ = 0; j_ < 8; ++j_)                                    \
                b8_[j_] = (short)bf16rne(w_[j_]);                             \
            acc[i_] = __builtin_amdgcn_mfma_f32_32x32x16_bf16(                \
                a8_, b8_, acc[i_], 0, 0, 0);                                  \
        }                                                                     \
    } while (0)

#define SUBITER(S, BIDX, FX0, FX1, NBIDX, NF0, NF1)                           \
    do {                                                                      \
        if ((S) == KS - 1) asm volatile("s_waitcnt vmcnt(0)" ::: "memory");   \
        else               asm volatile("s_waitcnt vmcnt(8)" ::: "memory");   \
        asm volatile("s_barrier" ::: "memory");                               \
        if ((S) + 2 < KS) {                                                   \
            ISSUE_STAGE(NBIDX, (S) + 2);                                      \
            NF0 = fbase[(size_t)((S) + 2) * 4];                               \
            NF1 = fbase[(size_t)((S) + 2) * 4 + 1];                           \
            FENCE();                                                          \
        }                                                                     \
        COMPUTE(BIDX, FX0, FX1);                                              \
    } while (0)

    float4 fA0, fA1, fB0, fB1, fC0, fC1;
    fC0 = make_float4(0.f, 0.f, 0.f, 0.f);
    fC1 = fC0;

    // prologue: groups 0 and 1 (group order pinned by fences)
    ISSUE_STAGE(0, 0);
    fA0 = fbase[0]; fA1 = fbase[1];
    FENCE();
    ISSUE_STAGE(1, 1);
    fB0 = fbase[4]; fB1 = fbase[5];
    FENCE();

    for (int st = 0; st < KS; st += 3) {
        SUBITER(st, 0, fA0, fA1, 2, fC0, fC1);
        if (st + 1 < KS) SUBITER(st + 1, 1, fB0, fB1, 0, fA0, fA1);
        if (st + 2 < KS) SUBITER(st + 2, 2, fC0, fC1, 1, fB0, fB1);
    }

    // epilogue: bf16-packed, lane-major (slot j = i*8+rp -> 2KB contiguous)
    unsigned* __restrict__ pp = partials + (size_t)(c * 2 + l) * PCHUNK;
#pragma unroll
    for (int i = 0; i < 3; ++i)
#pragma unroll
        for (int rp = 0; rp < 8; ++rp) {
            unsigned u = bf16rne(acc[i][2 * rp]) |
                         (bf16rne(acc[i][2 * rp + 1]) << 16);
            pp[(i * 8 + rp) * 512 + tid] = u;
        }
}

// Stage 2: unpack + reduce + bias. 24576 positions x 2 bf16 values each.
__global__ __launch_bounds__(256) void cc_stage2(
    const unsigned* __restrict__ partials,
    const float* __restrict__ bias,
    float* __restrict__ out)
{
    int t = blockIdx.x * 256 + threadIdx.x;   // 0 .. 24575
    if (t >= 2 * PCHUNK) return;
    int l   = t / PCHUNK;
    int rem = t - l * PCHUNK;
    int j   = rem >> 9;          // 0..23
    int tid = rem & 511;
    int wv = tid >> 6, lane = tid & 63, col = lane & 31, half = lane >> 5;
    int i = j >> 3, rp = j & 7;
    int r0 = 2 * rp, r1 = 2 * rp + 1;

    float s0 = 0.f, s1 = 0.f;
    const unsigned* __restrict__ p = partials + (size_t)l * PCHUNK + rem;
#pragma unroll 16
    for (int c = 0; c < NF; ++c, p += 2 * PCHUNK) {
        unsigned u = *p;
        s0 += __uint_as_float(u << 16);
        s1 += __uint_as_float(u & 0xffff0000u);
    }

    int d  = 96 * wv + 32 * i + col;
    int ld = l * DD + d;
    int b0 = (r0 & 3) + 8 * (r0 >> 2) + 4 * half;
    int b1 = (r1 & 3) + 8 * (r1 >> 2) + 4 * half;
    float bs = bias[ld];
    out[(size_t)b0 * LD + ld] = bs + s0;
    out[(size_t)b1 * LD + ld] = bs + s1;
}

// Correctness-only fallback if workspace is too small (fp32 path).
__global__ __launch_bounds__(256) void cc_direct(
    const float* __restrict__ f,
    const float* __restrict__ weight,
    const float* __restrict__ bias,
    float* __restrict__ out)
{
    int o = blockIdx.x * 256 + threadIdx.x;
    if (o >= BL) return;
    int b  = o / LD;
    int ld = o - b * LD;
    int l  = ld / DD;
    int d  = ld - l * DD;
    float s = bias[ld];
    const float* wp = weight + (size_t)l * FF * DD + d;
    const float* fp = f + (size_t)b * FF;
    for (int fi = 0; fi < FF; ++fi)
        s = fmaf(fp[fi], wp[(size_t)fi * DD], s);
    out[o] = s;
}

extern "C" void kernel_launch(void* const* d_in, const int* in_sizes, int n_in,
                              void* d_out, int out_size, void* d_ws, size_t ws_size,
                              hipStream_t stream)
{
    const float* f      = (const float*)d_in[0];   // 32 x 65536
    const float* weight = (const float*)d_in[1];   // 2 x 65536 x 768
    const float* bias   = (const float*)d_in[2];   // 2 x 768
    float* out          = (float*)d_out;           // 32 x 2 x 768

    if (ws_size < PART_BYTES) {
        cc_direct<<<(BL + 255) / 256, 256, 0, stream>>>(f, weight, bias, out);
        return;
    }

    unsigned* partials = (unsigned*)d_ws;

    dim3 grid1(NF, LL);
    cc_mfma<<<grid1, 512, 0, stream>>>((const float4*)f, weight, partials);

    cc_stage2<<<(2 * PCHUNK + 255) / 256, 256, 0, stream>>>(
        partials, bias, out);
}